// Round 1
// baseline (623.826 us; speedup 1.0000x reference)
//
#include <hip/hip_runtime.h>
#include <math.h>

#define DEPTH 6
#define HEADS 8
#define DIMH  64
#define BB    2
#define NN    128
#define EE    160
#define NF    127
#define DIMM  128
#define INNER 512

// ---------- helpers ----------

// block of 128 threads (2 waves): sum across all threads, result broadcast.
__device__ __forceinline__ float block_reduce_sum_128(float val, float* sbuf) {
#pragma unroll
    for (int off = 32; off > 0; off >>= 1) val += __shfl_xor(val, off, 64);
    int wave = threadIdx.x >> 6;
    int lane = threadIdx.x & 63;
    if (lane == 0) sbuf[wave] = val;
    __syncthreads();
    float r = sbuf[0] + sbuf[1];
    __syncthreads();
    return r;
}

// LayerNorm over 128 dims (per-thread value nd at dim d), then QKV projection
// for `layer`. Block = one node (bn), 128 threads. sbuf needs >= 130 floats:
// [0..1] reduce scratch, [2..129] xn share.
__device__ void ln_then_qkv(float nd, int d, int bn, int layer,
                            const float* ln1_g, const float* ln1_b,
                            const float* Wq, const float* bq,
                            const float* Wkv, const float* bkv,
                            float* qb, float* kb, float* vb, float* sbuf) {
    float m  = block_reduce_sum_128(nd, sbuf) * (1.0f / 128.0f);
    float df = nd - m;
    float var = block_reduce_sum_128(df * df, sbuf) * (1.0f / 128.0f);
    float xn = df * rsqrtf(var + 1e-5f) * ln1_g[layer * DIMM + d] + ln1_b[layer * DIMM + d];
    float* xsh = sbuf + 2;
    xsh[d] = xn;
    __syncthreads();

    const float* Wq_l  = Wq  + (size_t)layer * DIMM * INNER + d;
    const float* Wkv_l = Wkv + (size_t)layer * DIMM * 2 * INNER + d;
    const float* bq_l  = bq  + layer * INNER;
    const float* bkv_l = bkv + layer * 2 * INNER;

    float aq0 = bq_l[d],        aq1 = bq_l[128 + d],  aq2 = bq_l[256 + d],  aq3 = bq_l[384 + d];
    float ak0 = bkv_l[d],       ak1 = bkv_l[128 + d], ak2 = bkv_l[256 + d], ak3 = bkv_l[384 + d];
    float av0 = bkv_l[512 + d], av1 = bkv_l[640 + d], av2 = bkv_l[768 + d], av3 = bkv_l[896 + d];

    for (int kk = 0; kk < 128; kk++) {
        float xv = xsh[kk];
        const float* wq = Wq_l + kk * INNER;
        aq0 += xv * wq[0];   aq1 += xv * wq[128]; aq2 += xv * wq[256]; aq3 += xv * wq[384];
        const float* wkv = Wkv_l + kk * 1024;
        ak0 += xv * wkv[0];   ak1 += xv * wkv[128]; ak2 += xv * wkv[256]; ak3 += xv * wkv[384];
        av0 += xv * wkv[512]; av1 += xv * wkv[640]; av2 += xv * wkv[768]; av3 += xv * wkv[896];
    }
    float* qrow = qb + (size_t)bn * INNER;
    qrow[d] = aq0; qrow[128 + d] = aq1; qrow[256 + d] = aq2; qrow[384 + d] = aq3;
    float* krow = kb + (size_t)bn * INNER;
    krow[d] = ak0; krow[128 + d] = ak1; krow[256 + d] = ak2; krow[384 + d] = ak3;
    float* vrow = vb + (size_t)bn * INNER;
    vrow[d] = av0; vrow[128 + d] = av1; vrow[256 + d] = av2; vrow[384 + d] = av3;
    __syncthreads();
}

// ---------- kernels ----------

// Build nodes (atom_emb gather + noise) and LN1+QKV for layer 0.
__global__ __launch_bounds__(128) void k_pre(const int* indices, const float* noise,
                                             const float* atom_emb,
                                             const float* ln1_g, const float* ln1_b,
                                             const float* Wq, const float* bq,
                                             const float* Wkv, const float* bkv,
                                             float* nodes, float* qb, float* kb, float* vb) {
    int bn = blockIdx.x;
    int d  = threadIdx.x;
    __shared__ float s_red[130];
    int idx = indices[bn];
    float nd = (d < NF) ? atom_emb[idx * NF + d] : noise[0];
    nodes[bn * DIMM + d] = nd;
    ln_then_qkv(nd, d, bn, 0, ln1_g, ln1_b, Wq, bq, Wkv, bkv, qb, kb, vb, s_red);
}

// One block per (b,i) query row. 512 threads = 8 waves, wave h = head h,
// lane d = head-dim. Online softmax over j, edge features from bond list.
__global__ __launch_bounds__(512) void k_attn(int layer, const float* coords, const int* bonds,
                                              const float* We, const float* be,
                                              const float* qb, const float* kb, const float* vb,
                                              float* ao) {
    int bn = blockIdx.x;
    int b = bn >> 7, i = bn & 127;
    int tid = threadIdx.x;

    __shared__ float scoord[3 * NN];
    __shared__ float sedge[3 * NN];
    __shared__ int   sadj[NN];

    if (tid < 3 * NN) scoord[tid] = coords[b * 3 * NN + tid];
    if (tid < NN) sadj[tid] = 0;
    __syncthreads();
    if (tid < EE) {
        int e0 = bonds[2 * tid], e1 = bonds[2 * tid + 1];
        if (e0 == i) sadj[e1] = 1;
        if (e1 == i) sadj[e0] = 1;
    }
    __syncthreads();
    if (tid < NN) {
        int j = tid;
        float msk = sadj[j] ? 1.0f : 0.0f;
        sedge[3 * j + 0] = msk * (scoord[3 * i + 0] - scoord[3 * j + 0]);
        sedge[3 * j + 1] = msk * (scoord[3 * i + 1] - scoord[3 * j + 1]);
        sedge[3 * j + 2] = msk * (scoord[3 * i + 2] - scoord[3 * j + 2]);
    }
    __syncthreads();

    int hd = tid; // h*64 + d
    float qv  = qb[(size_t)bn * INNER + hd];
    float we0 = We[layer * 3 * INNER + hd];
    float we1 = We[layer * 3 * INNER + INNER + hd];
    float we2 = We[layer * 3 * INNER + 2 * INNER + hd];
    float bev = be[layer * INNER + hd];

    const float* krow = kb + (size_t)b * NN * INNER;
    const float* vrow = vb + (size_t)b * NN * INNER;

    float m_run = -1e30f, l_run = 0.0f, o_run = 0.0f;
    for (int j = 0; j < NN; j++) {
        float ex = sedge[3 * j], ey = sedge[3 * j + 1], ez = sedge[3 * j + 2];
        float e = bev + ex * we0 + ey * we1 + ez * we2;
        float s = qv * (krow[j * INNER + hd] + e);
#pragma unroll
        for (int off = 32; off > 0; off >>= 1) s += __shfl_xor(s, off, 64);
        s *= 0.125f; // DIM_HEAD^-0.5
        float nm = fmaxf(m_run, s);
        float alpha = __expf(m_run - nm);
        float p = __expf(s - nm);
        l_run = l_run * alpha + p;
        o_run = o_run * alpha + p * (vrow[j * INNER + hd] + e);
        m_run = nm;
    }
    ao[(size_t)bn * INNER + hd] = o_run / l_run;
}

// Per-node post-attention: Wo proj -> gate1 -> LN2 -> FF(gelu) -> gate2 ->
// nodes update; then LN1+QKV for next layer (if any).
__global__ __launch_bounds__(128) void k_post(int layer,
                                              const float* Wo, const float* bo, const float* Wg1,
                                              const float* ln2_g, const float* ln2_b,
                                              const float* W1, const float* b1,
                                              const float* W2, const float* b2,
                                              const float* Wg2,
                                              const float* ln1_g, const float* ln1_b,
                                              const float* Wq, const float* bq,
                                              const float* Wkv, const float* bkv,
                                              float* nodes, float* qb, float* kb, float* vb,
                                              const float* ao) {
    int bn = blockIdx.x;
    int d  = threadIdx.x;
    __shared__ float s_ao[INNER];
    __shared__ float s_h[INNER];
    __shared__ float s_red[130];

    const float* aorow = ao + (size_t)bn * INNER;
#pragma unroll
    for (int r = 0; r < 4; r++) s_ao[r * 128 + d] = aorow[r * 128 + d];
    __syncthreads();

    // out @ Wo + bo
    const float* Wo_l = Wo + (size_t)layer * INNER * DIMM + d;
    float x = bo[layer * DIMM + d];
    for (int kk = 0; kk < INNER; kk++) x += s_ao[kk] * Wo_l[kk * DIMM];

    // gated residual 1
    float res = nodes[bn * DIMM + d];
    const float* Wg1_l = Wg1 + layer * 3 * DIMM;
    float t = x * Wg1_l[d] + res * Wg1_l[DIMM + d] + (x - res) * Wg1_l[2 * DIMM + d];
    float g = block_reduce_sum_128(t, s_red);
    g = 1.0f / (1.0f + __expf(-g));
    float n1 = x * g + res * (1.0f - g);

    // LN2
    float m  = block_reduce_sum_128(n1, s_red) * (1.0f / 128.0f);
    float df = n1 - m;
    float var = block_reduce_sum_128(df * df, s_red) * (1.0f / 128.0f);
    float xn = df * rsqrtf(var + 1e-5f) * ln2_g[layer * DIMM + d] + ln2_b[layer * DIMM + d];
    s_red[2 + d] = xn;
    __syncthreads();

    // FF1 + exact gelu
    const float* W1_l = W1 + (size_t)layer * DIMM * 4 * DIMM + d;
    const float* b1_l = b1 + layer * 4 * DIMM;
    float a0 = b1_l[d], a1 = b1_l[128 + d], a2 = b1_l[256 + d], a3 = b1_l[384 + d];
    for (int kk = 0; kk < 128; kk++) {
        float xv = s_red[2 + kk];
        const float* w = W1_l + kk * 512;
        a0 += xv * w[0]; a1 += xv * w[128]; a2 += xv * w[256]; a3 += xv * w[384];
    }
    a0 = 0.5f * a0 * (1.0f + erff(a0 * 0.70710678f));
    a1 = 0.5f * a1 * (1.0f + erff(a1 * 0.70710678f));
    a2 = 0.5f * a2 * (1.0f + erff(a2 * 0.70710678f));
    a3 = 0.5f * a3 * (1.0f + erff(a3 * 0.70710678f));
    s_h[d] = a0; s_h[128 + d] = a1; s_h[256 + d] = a2; s_h[384 + d] = a3;
    __syncthreads();

    // FF2
    const float* W2_l = W2 + (size_t)layer * 4 * DIMM * DIMM + d;
    float y = b2[layer * DIMM + d];
    for (int kk = 0; kk < INNER; kk++) y += s_h[kk] * W2_l[kk * DIMM];

    // gated residual 2
    const float* Wg2_l = Wg2 + layer * 3 * DIMM;
    t = y * Wg2_l[d] + n1 * Wg2_l[DIMM + d] + (y - n1) * Wg2_l[2 * DIMM + d];
    float g2 = block_reduce_sum_128(t, s_red);
    g2 = 1.0f / (1.0f + __expf(-g2));
    float n2 = y * g2 + n1 * (1.0f - g2);
    nodes[bn * DIMM + d] = n2;
    __syncthreads();

    if (layer < DEPTH - 1) {
        ln_then_qkv(n2, d, bn, layer + 1, ln1_g, ln1_b, Wq, bq, Wkv, bkv, qb, kb, vb, s_red);
    }
}

// Final: sum over nodes of (nodes @ Wlin + blin) -> scalar.
__global__ __launch_bounds__(256) void k_final(const float* nodes, const float* Wlin,
                                               const float* blin, float* out) {
    int t = threadIdx.x; // 0..255 = node index
    float s = blin[0];
    const float* nr = nodes + t * DIMM;
    for (int d = 0; d < DIMM; d++) s += nr[d] * Wlin[d];
#pragma unroll
    for (int off = 32; off > 0; off >>= 1) s += __shfl_xor(s, off, 64);
    __shared__ float sb[4];
    int wave = t >> 6, lane = t & 63;
    if (lane == 0) sb[wave] = s;
    __syncthreads();
    if (t == 0) out[0] = sb[0] + sb[1] + sb[2] + sb[3];
}

extern "C" void kernel_launch(void* const* d_in, const int* in_sizes, int n_in,
                              void* d_out, int out_size, void* d_ws, size_t ws_size,
                              hipStream_t stream) {
    const int*   indices = (const int*)d_in[0];
    const float* coords  = (const float*)d_in[1];
    const int*   bonds   = (const int*)d_in[2];
    const float* noise   = (const float*)d_in[3];
    const float* atom_emb= (const float*)d_in[4];
    const float* ln1_g   = (const float*)d_in[5];
    const float* ln1_b   = (const float*)d_in[6];
    const float* Wq      = (const float*)d_in[7];
    const float* bq      = (const float*)d_in[8];
    const float* Wkv     = (const float*)d_in[9];
    const float* bkv     = (const float*)d_in[10];
    const float* We      = (const float*)d_in[11];
    const float* be      = (const float*)d_in[12];
    const float* Wo      = (const float*)d_in[13];
    const float* bo      = (const float*)d_in[14];
    const float* Wg1     = (const float*)d_in[15];
    const float* ln2_g   = (const float*)d_in[16];
    const float* ln2_b   = (const float*)d_in[17];
    const float* W1      = (const float*)d_in[18];
    const float* b1      = (const float*)d_in[19];
    const float* W2      = (const float*)d_in[20];
    const float* b2      = (const float*)d_in[21];
    const float* Wg2     = (const float*)d_in[22];
    const float* Wlin    = (const float*)d_in[23];
    const float* blin    = (const float*)d_in[24];

    float* ws    = (float*)d_ws;
    float* nodes = ws;                               // B*N*DIM   = 32768
    float* qb    = nodes + BB * NN * DIMM;           // B*N*INNER = 131072
    float* kb    = qb + BB * NN * INNER;
    float* vb    = kb + BB * NN * INNER;
    float* ao    = vb + BB * NN * INNER;

    k_pre<<<BB * NN, 128, 0, stream>>>(indices, noise, atom_emb, ln1_g, ln1_b,
                                       Wq, bq, Wkv, bkv, nodes, qb, kb, vb);
    for (int l = 0; l < DEPTH; l++) {
        k_attn<<<BB * NN, 512, 0, stream>>>(l, coords, bonds, We, be, qb, kb, vb, ao);
        k_post<<<BB * NN, 128, 0, stream>>>(l, Wo, bo, Wg1, ln2_g, ln2_b, W1, b1, W2, b2,
                                            Wg2, ln1_g, ln1_b, Wq, bq, Wkv, bkv,
                                            nodes, qb, kb, vb, ao);
    }
    k_final<<<1, 256, 0, stream>>>(nodes, Wlin, blin, (float*)d_out);
}

// Round 2
// 519.051 us; speedup vs baseline: 1.2019x; 1.2019x over previous
//
#include <hip/hip_runtime.h>
#include <math.h>

#define DEPTH 6
#define HEADS 8
#define DIMH  64
#define BB    2
#define NN    128
#define EE    160
#define NF    127
#define DIMM  128
#define INNER 512

// ---------- helpers ----------

// 8-wave (512-thread) block sum; result broadcast to all threads.
__device__ __forceinline__ float block_reduce_sum_8w(float val, float* sbuf) {
#pragma unroll
    for (int off = 32; off > 0; off >>= 1) val += __shfl_xor(val, off, 64);
    int wave = threadIdx.x >> 6;
    int lane = threadIdx.x & 63;
    if (lane == 0) sbuf[wave] = val;
    __syncthreads();
    float r = sbuf[0] + sbuf[1] + sbuf[2] + sbuf[3] + sbuf[4] + sbuf[5] + sbuf[6] + sbuf[7];
    __syncthreads();
    return r;
}

// 512-thread LN over 128 dims + QKV projection for `layer`.
// t in [0,512), d = t&127, kq = t>>7. nd: per-thread copy of node value at dim d
// (replicated across the 4 kq groups). s_xn: 128-float LDS, s_red: 8-float LDS.
__device__ void ln_qkv_512(float nd, int t, int d, int kq, int bn, int layer,
                           const float* ln1_g, const float* ln1_b,
                           const float* Wq, const float* bq,
                           const float* Wkv, const float* bkv,
                           float* qb, float* kb, float* vb,
                           float* s_xn, float* s_red) {
    float m   = block_reduce_sum_8w((kq == 0) ? nd : 0.0f, s_red) * (1.0f / 128.0f);
    float df  = nd - m;
    float var = block_reduce_sum_8w((kq == 0) ? df * df : 0.0f, s_red) * (1.0f / 128.0f);
    float xn  = df * rsqrtf(var + 1e-5f) * ln1_g[layer * DIMM + d] + ln1_b[layer * DIMM + d];
    if (kq == 0) s_xn[d] = xn;
    __syncthreads();

    const float* Wq_l  = Wq  + (size_t)layer * DIMM * INNER + t;
    const float* Wkv_l = Wkv + (size_t)layer * DIMM * 2 * INNER + t;
    float aq = bq[layer * INNER + t];
    float ak = bkv[layer * 2 * INNER + t];
    float av = bkv[layer * 2 * INNER + INNER + t];
#pragma unroll 4
    for (int kk = 0; kk < 128; kk++) {
        float xv = s_xn[kk];
        aq += xv * Wq_l[kk * INNER];
        ak += xv * Wkv_l[kk * 2 * INNER];
        av += xv * Wkv_l[kk * 2 * INNER + INNER];
    }
    qb[(size_t)bn * INNER + t] = aq;
    kb[(size_t)bn * INNER + t] = ak;
    vb[(size_t)bn * INNER + t] = av;
}

// ---------- kernels ----------

__global__ __launch_bounds__(512) void k_pre(const int* indices, const float* noise,
                                             const float* atom_emb,
                                             const float* ln1_g, const float* ln1_b,
                                             const float* Wq, const float* bq,
                                             const float* Wkv, const float* bkv,
                                             float* nodes, float* qb, float* kb, float* vb) {
    int bn = blockIdx.x;
    int t  = threadIdx.x;
    int d  = t & 127;
    int kq = t >> 7;
    __shared__ float s_xn[128];
    __shared__ float s_red[8];
    int idx = indices[bn];
    float nd = (d < NF) ? atom_emb[idx * NF + d] : noise[0];
    if (kq == 0) nodes[bn * DIMM + d] = nd;
    ln_qkv_512(nd, t, d, kq, bn, 0, ln1_g, ln1_b, Wq, bq, Wkv, bkv, qb, kb, vb, s_xn, s_red);
}

// One block per (b,i) query row. 1024 threads = 16 waves: wave-group jg (0/1)
// handles j in [jg*64, jg*64+64); within a group, wave h = head, lane = dim.
// Softmax without max-tracking (|sim| small), so partial (l, o) sums merge by
// plain addition.
__global__ __launch_bounds__(1024) void k_attn(int layer, const float* coords, const int* bonds,
                                               const float* We, const float* be,
                                               const float* qb, const float* kb, const float* vb,
                                               float* ao) {
    int bn = blockIdx.x;
    int b = bn >> 7, i = bn & 127;
    int tid = threadIdx.x;
    int jg = tid >> 9;
    int hd = tid & 511;

    __shared__ float scoord[3 * NN];
    __shared__ float sedge[3 * NN];
    __shared__ int   sadj[NN];
    __shared__ float s_o[2][INNER];
    __shared__ float s_l[2][HEADS];

    if (tid < 3 * NN) scoord[tid] = coords[b * 3 * NN + tid];
    if (tid < NN) sadj[tid] = 0;
    __syncthreads();
    if (tid < EE) {
        int e0 = bonds[2 * tid], e1 = bonds[2 * tid + 1];
        if (e0 == i) sadj[e1] = 1;
        if (e1 == i) sadj[e0] = 1;
    }
    __syncthreads();
    if (tid < NN) {
        int j = tid;
        float msk = sadj[j] ? 1.0f : 0.0f;
        sedge[3 * j + 0] = msk * (scoord[3 * i + 0] - scoord[3 * j + 0]);
        sedge[3 * j + 1] = msk * (scoord[3 * i + 1] - scoord[3 * j + 1]);
        sedge[3 * j + 2] = msk * (scoord[3 * i + 2] - scoord[3 * j + 2]);
    }
    __syncthreads();

    float qv  = qb[(size_t)bn * INNER + hd];
    float we0 = We[layer * 3 * INNER + hd];
    float we1 = We[layer * 3 * INNER + INNER + hd];
    float we2 = We[layer * 3 * INNER + 2 * INNER + hd];
    float bev = be[layer * INNER + hd];

    const float* krow = kb + (size_t)b * NN * INNER;
    const float* vrow = vb + (size_t)b * NN * INNER;

    float l_run = 0.0f, o_run = 0.0f;
    int j0 = jg * 64;
    for (int jj = 0; jj < 64; jj += 2) {
        int j = j0 + jj;
        float e0 = bev + sedge[3 * j + 0] * we0 + sedge[3 * j + 1] * we1 + sedge[3 * j + 2] * we2;
        float e1 = bev + sedge[3 * j + 3] * we0 + sedge[3 * j + 4] * we1 + sedge[3 * j + 5] * we2;
        float s0 = qv * (krow[(size_t)j * INNER + hd] + e0);
        float s1 = qv * (krow[(size_t)(j + 1) * INNER + hd] + e1);
#pragma unroll
        for (int off = 32; off > 0; off >>= 1) {
            s0 += __shfl_xor(s0, off, 64);
            s1 += __shfl_xor(s1, off, 64);
        }
        float p0 = __expf(s0 * 0.125f);
        float p1 = __expf(s1 * 0.125f);
        l_run += p0 + p1;
        o_run += p0 * (vrow[(size_t)j * INNER + hd] + e0)
               + p1 * (vrow[(size_t)(j + 1) * INNER + hd] + e1);
    }
    s_o[jg][hd] = o_run;
    if ((tid & 63) == 0) s_l[jg][hd >> 6] = l_run;
    __syncthreads();
    if (jg == 0) {
        float l = l_run + s_l[1][hd >> 6];
        float o = o_run + s_o[1][hd];
        ao[(size_t)bn * INNER + hd] = o / l;
    }
}

// Per-node post-attention with 512 threads: Wo proj (K split 4-way) -> gate1 ->
// LN2 -> FF1 (1 out/thread) -> gelu -> FF2 (K split 4-way) -> gate2 -> nodes;
// then LN1+QKV for next layer.
__global__ __launch_bounds__(512) void k_post(int layer,
                                              const float* Wo, const float* bo, const float* Wg1,
                                              const float* ln2_g, const float* ln2_b,
                                              const float* W1, const float* b1,
                                              const float* W2, const float* b2,
                                              const float* Wg2,
                                              const float* ln1_g, const float* ln1_b,
                                              const float* Wq, const float* bq,
                                              const float* Wkv, const float* bkv,
                                              float* nodes, float* qb, float* kb, float* vb,
                                              const float* ao) {
    int bn = blockIdx.x;
    int t  = threadIdx.x;
    int d  = t & 127;
    int kq = t >> 7;
    int k0 = kq * 128;

    __shared__ float s_ao[INNER];
    __shared__ float s_h[INNER];
    __shared__ float s_part[4][128];
    __shared__ float s_xn[128];
    __shared__ float s_red[8];

    s_ao[t] = ao[(size_t)bn * INNER + t];
    float res = nodes[bn * DIMM + d];
    __syncthreads();

    // out @ Wo + bo, K=512 split across kq
    const float* Wo_l = Wo + (size_t)layer * INNER * DIMM + d;
    float xp = 0.0f;
#pragma unroll 4
    for (int kk = 0; kk < 128; kk++) xp += s_ao[k0 + kk] * Wo_l[(k0 + kk) * DIMM];
    s_part[kq][d] = xp;
    __syncthreads();
    float x = bo[layer * DIMM + d] + s_part[0][d] + s_part[1][d] + s_part[2][d] + s_part[3][d];

    // gated residual 1
    const float* Wg1_l = Wg1 + layer * 3 * DIMM;
    float texpr = x * Wg1_l[d] + res * Wg1_l[DIMM + d] + (x - res) * Wg1_l[2 * DIMM + d];
    float g = block_reduce_sum_8w((kq == 0) ? texpr : 0.0f, s_red);
    g = 1.0f / (1.0f + __expf(-g));
    float n1 = x * g + res * (1.0f - g);

    // LN2
    float m   = block_reduce_sum_8w((kq == 0) ? n1 : 0.0f, s_red) * (1.0f / 128.0f);
    float df  = n1 - m;
    float var = block_reduce_sum_8w((kq == 0) ? df * df : 0.0f, s_red) * (1.0f / 128.0f);
    float xn  = df * rsqrtf(var + 1e-5f) * ln2_g[layer * DIMM + d] + ln2_b[layer * DIMM + d];
    if (kq == 0) s_xn[d] = xn;
    __syncthreads();

    // FF1 + exact gelu: one output per thread, K=128
    const float* W1_l = W1 + (size_t)layer * DIMM * 4 * DIMM + t;
    float a = b1[layer * 4 * DIMM + t];
#pragma unroll 4
    for (int kk = 0; kk < 128; kk++) a += s_xn[kk] * W1_l[kk * 4 * DIMM];
    a = 0.5f * a * (1.0f + erff(a * 0.70710678f));
    s_h[t] = a;
    __syncthreads();

    // FF2: K=512 split across kq
    const float* W2_l = W2 + (size_t)layer * 4 * DIMM * DIMM + d;
    float yp = 0.0f;
#pragma unroll 4
    for (int kk = 0; kk < 128; kk++) yp += s_h[k0 + kk] * W2_l[(k0 + kk) * DIMM];
    s_part[kq][d] = yp;
    __syncthreads();
    float y = b2[layer * DIMM + d] + s_part[0][d] + s_part[1][d] + s_part[2][d] + s_part[3][d];

    // gated residual 2
    const float* Wg2_l = Wg2 + layer * 3 * DIMM;
    texpr = y * Wg2_l[d] + n1 * Wg2_l[DIMM + d] + (y - n1) * Wg2_l[2 * DIMM + d];
    float g2 = block_reduce_sum_8w((kq == 0) ? texpr : 0.0f, s_red);
    g2 = 1.0f / (1.0f + __expf(-g2));
    float n2 = y * g2 + n1 * (1.0f - g2);
    if (kq == 0) nodes[bn * DIMM + d] = n2;

    if (layer < DEPTH - 1) {
        ln_qkv_512(n2, t, d, kq, bn, layer + 1, ln1_g, ln1_b, Wq, bq, Wkv, bkv,
                   qb, kb, vb, s_xn, s_red);
    }
}

// Final: sum over nodes of (nodes @ Wlin + blin) -> scalar.
__global__ __launch_bounds__(256) void k_final(const float* nodes, const float* Wlin,
                                               const float* blin, float* out) {
    int t = threadIdx.x; // 0..255 = node index
    float s = blin[0];
    const float* nr = nodes + t * DIMM;
    for (int d = 0; d < DIMM; d++) s += nr[d] * Wlin[d];
#pragma unroll
    for (int off = 32; off > 0; off >>= 1) s += __shfl_xor(s, off, 64);
    __shared__ float sb[4];
    int wave = t >> 6, lane = t & 63;
    if (lane == 0) sb[wave] = s;
    __syncthreads();
    if (t == 0) out[0] = sb[0] + sb[1] + sb[2] + sb[3];
}

extern "C" void kernel_launch(void* const* d_in, const int* in_sizes, int n_in,
                              void* d_out, int out_size, void* d_ws, size_t ws_size,
                              hipStream_t stream) {
    const int*   indices = (const int*)d_in[0];
    const float* coords  = (const float*)d_in[1];
    const int*   bonds   = (const int*)d_in[2];
    const float* noise   = (const float*)d_in[3];
    const float* atom_emb= (const float*)d_in[4];
    const float* ln1_g   = (const float*)d_in[5];
    const float* ln1_b   = (const float*)d_in[6];
    const float* Wq      = (const float*)d_in[7];
    const float* bq      = (const float*)d_in[8];
    const float* Wkv     = (const float*)d_in[9];
    const float* bkv     = (const float*)d_in[10];
    const float* We      = (const float*)d_in[11];
    const float* be      = (const float*)d_in[12];
    const float* Wo      = (const float*)d_in[13];
    const float* bo      = (const float*)d_in[14];
    const float* Wg1     = (const float*)d_in[15];
    const float* ln2_g   = (const float*)d_in[16];
    const float* ln2_b   = (const float*)d_in[17];
    const float* W1      = (const float*)d_in[18];
    const float* b1      = (const float*)d_in[19];
    const float* W2      = (const float*)d_in[20];
    const float* b2      = (const float*)d_in[21];
    const float* Wg2     = (const float*)d_in[22];
    const float* Wlin    = (const float*)d_in[23];
    const float* blin    = (const float*)d_in[24];

    float* ws    = (float*)d_ws;
    float* nodes = ws;                               // B*N*DIM   = 32768
    float* qb    = nodes + BB * NN * DIMM;           // B*N*INNER = 131072
    float* kb    = qb + BB * NN * INNER;
    float* vb    = kb + BB * NN * INNER;
    float* ao    = vb + BB * NN * INNER;

    k_pre<<<BB * NN, 512, 0, stream>>>(indices, noise, atom_emb, ln1_g, ln1_b,
                                       Wq, bq, Wkv, bkv, nodes, qb, kb, vb);
    for (int l = 0; l < DEPTH; l++) {
        k_attn<<<BB * NN, 1024, 0, stream>>>(l, coords, bonds, We, be, qb, kb, vb, ao);
        k_post<<<BB * NN, 512, 0, stream>>>(l, Wo, bo, Wg1, ln2_g, ln2_b, W1, b1, W2, b2,
                                            Wg2, ln1_g, ln1_b, Wq, bq, Wkv, bkv,
                                            nodes, qb, kb, vb, ao);
    }
    k_final<<<1, 256, 0, stream>>>(nodes, Wlin, blin, (float*)d_out);
}

// Round 3
// 318.956 us; speedup vs baseline: 1.9558x; 1.6273x over previous
//
#include <hip/hip_runtime.h>
#include <math.h>

#define DEPTH 6
#define HEADS 8
#define DIMH  64
#define BB    2
#define NN    128
#define EE    160
#define NF    127
#define DIMM  128
#define INNER 512

// ---------- helpers ----------

// 8-wave (512-thread) block sum; result broadcast to all threads.
__device__ __forceinline__ float block_reduce_sum_8w(float val, float* sbuf) {
#pragma unroll
    for (int off = 32; off > 0; off >>= 1) val += __shfl_xor(val, off, 64);
    int wave = threadIdx.x >> 6;
    int lane = threadIdx.x & 63;
    if (lane == 0) sbuf[wave] = val;
    __syncthreads();
    float r = sbuf[0] + sbuf[1] + sbuf[2] + sbuf[3] + sbuf[4] + sbuf[5] + sbuf[6] + sbuf[7];
    __syncthreads();
    return r;
}

// LN over 128 dims + QKV projection (float4 weight loads, K split 4-way).
// 512 threads. nd = node value at d=t&127 (valid for t<128; others pass 0).
// s_part: 3 buffers of 2048 floats.
__device__ void ln_qkv_f4(float nd, int t, int bn, int layer,
                          const float* ln1_g, const float* ln1_b,
                          const float* Wq, const float* bq,
                          const float* Wkv, const float* bkv,
                          float* qb, float* kb, float* vb,
                          float* s_xn, float* s_red, float* s_part) {
    int d   = t & 127;
    bool own = (t < 128);
    float m   = block_reduce_sum_8w(own ? nd : 0.0f, s_red) * (1.0f / 128.0f);
    float df  = nd - m;
    float var = block_reduce_sum_8w(own ? df * df : 0.0f, s_red) * (1.0f / 128.0f);
    float xn  = df * rsqrtf(var + 1e-5f) * ln1_g[layer * DIMM + d] + ln1_b[layer * DIMM + d];
    if (own) s_xn[d] = xn;
    __syncthreads();

    int c7  = t & 127;   // output quad index (o = 4*c7..4*c7+3)
    int kg  = t >> 7;    // 4 K-groups of 32
    int kkb = kg * 32;
    const float4* WqR  = (const float4*)(Wq  + (size_t)layer * DIMM * INNER);
    const float4* WkvR = (const float4*)(Wkv + (size_t)layer * DIMM * 2 * INNER);
    float4 aq = {0, 0, 0, 0}, ak = {0, 0, 0, 0}, av = {0, 0, 0, 0};
#pragma unroll 8
    for (int r = 0; r < 32; r++) {
        int kk = kkb + r;
        float a = s_xn[kk];
        float4 wq = WqR[kk * 128 + c7];
        float4 wk = WkvR[kk * 256 + c7];
        float4 wv = WkvR[kk * 256 + 128 + c7];
        aq.x += a * wq.x; aq.y += a * wq.y; aq.z += a * wq.z; aq.w += a * wq.w;
        ak.x += a * wk.x; ak.y += a * wk.y; ak.z += a * wk.z; ak.w += a * wk.w;
        av.x += a * wv.x; av.y += a * wv.y; av.z += a * wv.z; av.w += a * wv.w;
    }
    ((float4*)(s_part + 0 * 2048 + kg * 512 + 4 * c7))[0] = aq;
    ((float4*)(s_part + 1 * 2048 + kg * 512 + 4 * c7))[0] = ak;
    ((float4*)(s_part + 2 * 2048 + kg * 512 + 4 * c7))[0] = av;
    __syncthreads();
    // combine: thread t = output o
    float q = bq[layer * INNER + t];
    float k = bkv[layer * 2 * INNER + t];
    float v = bkv[layer * 2 * INNER + INNER + t];
#pragma unroll
    for (int g = 0; g < 4; g++) {
        q += s_part[0 * 2048 + g * 512 + t];
        k += s_part[1 * 2048 + g * 512 + t];
        v += s_part[2 * 2048 + g * 512 + t];
    }
    qb[(size_t)bn * INNER + t] = q;
    kb[(size_t)bn * INNER + t] = k;
    vb[(size_t)bn * INNER + t] = v;
}

// ---------- kernels ----------

__global__ __launch_bounds__(512) void k_pre(const int* indices, const float* noise,
                                             const float* atom_emb,
                                             const float* ln1_g, const float* ln1_b,
                                             const float* Wq, const float* bq,
                                             const float* Wkv, const float* bkv,
                                             float* nodes, float* qb, float* kb, float* vb) {
    int bn = blockIdx.x;
    int t  = threadIdx.x;
    int d  = t & 127;
    __shared__ float s_xn[128];
    __shared__ float s_red[8];
    __shared__ float s_part[3 * 2048];
    int idx = indices[bn];
    float nd = (d < NF) ? atom_emb[idx * NF + d] : noise[0];
    if (t < 128) nodes[bn * DIMM + d] = nd;
    ln_qkv_f4(nd, t, bn, 0, ln1_g, ln1_b, Wq, bq, Wkv, bkv, qb, kb, vb, s_xn, s_red, s_part);
}

// One block per (b,i) query row. 1024 threads: 8 j-groups x 128 threads.
// Thread owns a head-dim quad (hd = 4c..4c+3); 16 lanes per head ->
// 4-stage shuffle reduce. Softmax without max-tracking (|sim| small).
__global__ __launch_bounds__(1024) void k_attn(int layer, const float* coords, const int* bonds,
                                               const float* We, const float* be,
                                               const float* qb, const float* kb, const float* vb,
                                               float* ao) {
    int bn = blockIdx.x;
    int b = bn >> 7, i = bn & 127;
    int tid = threadIdx.x;
    int jg = tid >> 7;   // 0..7
    int c  = tid & 127;  // quad index, head h = c>>4
    int h  = c >> 4;

    __shared__ float scoord[3 * NN];
    __shared__ float sedge[3 * NN];
    __shared__ int   sadj[NN];
    __shared__ float s_o[8 * INNER];
    __shared__ float s_l[8 * HEADS];

    if (tid < 3 * NN) scoord[tid] = coords[b * 3 * NN + tid];
    if (tid < NN) sadj[tid] = 0;
    __syncthreads();
    if (tid < EE) {
        int e0 = bonds[2 * tid], e1 = bonds[2 * tid + 1];
        if (e0 == i) sadj[e1] = 1;
        if (e1 == i) sadj[e0] = 1;
    }
    __syncthreads();
    if (tid < NN) {
        int j = tid;
        float msk = sadj[j] ? 1.0f : 0.0f;
        sedge[3 * j + 0] = msk * (scoord[3 * i + 0] - scoord[3 * j + 0]);
        sedge[3 * j + 1] = msk * (scoord[3 * i + 1] - scoord[3 * j + 1]);
        sedge[3 * j + 2] = msk * (scoord[3 * i + 2] - scoord[3 * j + 2]);
    }
    __syncthreads();

    const float4* qR  = (const float4*)(qb + (size_t)bn * INNER);
    const float4* WeR = (const float4*)(We + (size_t)layer * 3 * INNER);
    float4 qv  = qR[c];
    float4 we0 = WeR[c], we1 = WeR[128 + c], we2 = WeR[256 + c];
    float4 bev = ((const float4*)(be + (size_t)layer * INNER))[c];
    const float4* kR = (const float4*)(kb + (size_t)b * NN * INNER);
    const float4* vR = (const float4*)(vb + (size_t)b * NN * INNER);

    float l_run = 0.0f;
    float4 o_run = {0, 0, 0, 0};
    int j0 = jg * 16;
#pragma unroll 4
    for (int jj = 0; jj < 16; jj++) {
        int j = j0 + jj;
        float ex = sedge[3 * j], ey = sedge[3 * j + 1], ez = sedge[3 * j + 2];
        float4 e;
        e.x = bev.x + ex * we0.x + ey * we1.x + ez * we2.x;
        e.y = bev.y + ex * we0.y + ey * we1.y + ez * we2.y;
        e.z = bev.z + ex * we0.z + ey * we1.z + ez * we2.z;
        e.w = bev.w + ex * we0.w + ey * we1.w + ez * we2.w;
        float4 kv = kR[j * 128 + c];
        float s = (qv.x * (kv.x + e.x) + qv.y * (kv.y + e.y))
                + (qv.z * (kv.z + e.z) + qv.w * (kv.w + e.w));
        s += __shfl_xor(s, 1, 64);
        s += __shfl_xor(s, 2, 64);
        s += __shfl_xor(s, 4, 64);
        s += __shfl_xor(s, 8, 64);
        float p = __expf(s * 0.125f);
        float4 vv = vR[j * 128 + c];
        l_run += p;
        o_run.x += p * (vv.x + e.x);
        o_run.y += p * (vv.y + e.y);
        o_run.z += p * (vv.z + e.z);
        o_run.w += p * (vv.w + e.w);
    }
    ((float4*)(s_o + jg * INNER))[c] = o_run;
    if ((c & 15) == 0) s_l[jg * HEADS + h] = l_run;
    __syncthreads();
    if (jg == 0) {
        float4 o = o_run;
        float l = l_run;
#pragma unroll
        for (int g = 1; g < 8; g++) {
            float4 og = ((float4*)(s_o + g * INNER))[c];
            o.x += og.x; o.y += og.y; o.z += og.z; o.w += og.w;
            l += s_l[g * HEADS + h];
        }
        float inv = 1.0f / l;
        float4 r; r.x = o.x * inv; r.y = o.y * inv; r.z = o.z * inv; r.w = o.w * inv;
        ((float4*)(ao + (size_t)bn * INNER))[c] = r;
    }
}

// Per-node post-attention, float4 weight loads throughout.
__global__ __launch_bounds__(512) void k_post(int layer,
                                              const float* Wo, const float* bo, const float* Wg1,
                                              const float* ln2_g, const float* ln2_b,
                                              const float* W1, const float* b1,
                                              const float* W2, const float* b2,
                                              const float* Wg2,
                                              const float* ln1_g, const float* ln1_b,
                                              const float* Wq, const float* bq,
                                              const float* Wkv, const float* bkv,
                                              float* nodes, float* qb, float* kb, float* vb,
                                              const float* ao) {
    int bn = blockIdx.x;
    int t  = threadIdx.x;
    int d  = t & 127;
    bool own = (t < 128);

    __shared__ float s_ao[INNER];
    __shared__ float s_h[INNER];
    __shared__ float s_xn[128];
    __shared__ float s_red[8];
    __shared__ float s_part[3 * 2048];

    s_ao[t] = ao[(size_t)bn * INNER + t];
    float res = own ? nodes[bn * DIMM + d] : 0.0f;
    __syncthreads();

    // ---- Wo-proj: x[d] = bo + sum_k ao[k] * Wo[k][d]. c5 = column quad, 16 K-groups.
    int c5  = t & 31;
    int kg16 = t >> 5;
    {
        const float4* WoR = (const float4*)(Wo + (size_t)layer * INNER * DIMM);
        float4 acc = {0, 0, 0, 0};
        int kkb = kg16 * 32;
#pragma unroll 8
        for (int r = 0; r < 32; r++) {
            int kk = kkb + r;
            float a = s_ao[kk];
            float4 w = WoR[kk * 32 + c5];
            acc.x += a * w.x; acc.y += a * w.y; acc.z += a * w.z; acc.w += a * w.w;
        }
        ((float4*)(s_part + kg16 * 128 + 4 * c5))[0] = acc;
    }
    __syncthreads();
    float x = 0.0f;
    if (own) {
        x = bo[layer * DIMM + d];
#pragma unroll
        for (int g = 0; g < 16; g++) x += s_part[g * 128 + d];
    }

    // ---- gated residual 1
    const float* Wg1_l = Wg1 + layer * 3 * DIMM;
    float texpr = own ? (x * Wg1_l[d] + res * Wg1_l[DIMM + d] + (x - res) * Wg1_l[2 * DIMM + d]) : 0.0f;
    float g1 = block_reduce_sum_8w(texpr, s_red);
    g1 = 1.0f / (1.0f + __expf(-g1));
    float n1 = x * g1 + res * (1.0f - g1);

    // ---- LN2
    float m   = block_reduce_sum_8w(own ? n1 : 0.0f, s_red) * (1.0f / 128.0f);
    float df  = n1 - m;
    float var = block_reduce_sum_8w(own ? df * df : 0.0f, s_red) * (1.0f / 128.0f);
    float xn  = df * rsqrtf(var + 1e-5f) * ln2_g[layer * DIMM + d] + ln2_b[layer * DIMM + d];
    if (own) s_xn[d] = xn;
    __syncthreads();

    // ---- FF1 + gelu: o = 4*c7.. , 4 K-groups of 32
    int c7 = t & 127;
    int kg4 = t >> 7;
    {
        const float4* W1R = (const float4*)(W1 + (size_t)layer * DIMM * 4 * DIMM);
        float4 acc = {0, 0, 0, 0};
        int kkb = kg4 * 32;
#pragma unroll 8
        for (int r = 0; r < 32; r++) {
            int kk = kkb + r;
            float a = s_xn[kk];
            float4 w = W1R[kk * 128 + c7];
            acc.x += a * w.x; acc.y += a * w.y; acc.z += a * w.z; acc.w += a * w.w;
        }
        ((float4*)(s_part + kg4 * 512 + 4 * c7))[0] = acc;
    }
    __syncthreads();
    {
        float a = b1[layer * 4 * DIMM + t];
#pragma unroll
        for (int g = 0; g < 4; g++) a += s_part[g * 512 + t];
        a = 0.5f * a * (1.0f + erff(a * 0.70710678f));
        s_h[t] = a;
    }
    __syncthreads();

    // ---- FF2: same shape as Wo
    {
        const float4* W2R = (const float4*)(W2 + (size_t)layer * 4 * DIMM * DIMM);
        float4 acc = {0, 0, 0, 0};
        int kkb = kg16 * 32;
#pragma unroll 8
        for (int r = 0; r < 32; r++) {
            int kk = kkb + r;
            float a = s_h[kk];
            float4 w = W2R[kk * 32 + c5];
            acc.x += a * w.x; acc.y += a * w.y; acc.z += a * w.z; acc.w += a * w.w;
        }
        ((float4*)(s_part + kg16 * 128 + 4 * c5))[0] = acc;
    }
    __syncthreads();
    float y = 0.0f;
    if (own) {
        y = b2[layer * DIMM + d];
#pragma unroll
        for (int g = 0; g < 16; g++) y += s_part[g * 128 + d];
    }

    // ---- gated residual 2
    const float* Wg2_l = Wg2 + layer * 3 * DIMM;
    texpr = own ? (y * Wg2_l[d] + n1 * Wg2_l[DIMM + d] + (y - n1) * Wg2_l[2 * DIMM + d]) : 0.0f;
    float g2 = block_reduce_sum_8w(texpr, s_red);
    g2 = 1.0f / (1.0f + __expf(-g2));
    float n2 = y * g2 + n1 * (1.0f - g2);
    if (own) nodes[bn * DIMM + d] = n2;

    if (layer < DEPTH - 1) {
        ln_qkv_f4(own ? n2 : 0.0f, t, bn, layer + 1, ln1_g, ln1_b, Wq, bq, Wkv, bkv,
                  qb, kb, vb, s_xn, s_red, s_part);
    }
}

// Final: sum over nodes of (nodes @ Wlin + blin) -> scalar.
__global__ __launch_bounds__(256) void k_final(const float* nodes, const float* Wlin,
                                               const float* blin, float* out) {
    int t = threadIdx.x; // 0..255 = node index
    float s = blin[0];
    const float* nr = nodes + t * DIMM;
    for (int d = 0; d < DIMM; d++) s += nr[d] * Wlin[d];
#pragma unroll
    for (int off = 32; off > 0; off >>= 1) s += __shfl_xor(s, off, 64);
    __shared__ float sb[4];
    int wave = t >> 6, lane = t & 63;
    if (lane == 0) sb[wave] = s;
    __syncthreads();
    if (t == 0) out[0] = sb[0] + sb[1] + sb[2] + sb[3];
}

extern "C" void kernel_launch(void* const* d_in, const int* in_sizes, int n_in,
                              void* d_out, int out_size, void* d_ws, size_t ws_size,
                              hipStream_t stream) {
    const int*   indices = (const int*)d_in[0];
    const float* coords  = (const float*)d_in[1];
    const int*   bonds   = (const int*)d_in[2];
    const float* noise   = (const float*)d_in[3];
    const float* atom_emb= (const float*)d_in[4];
    const float* ln1_g   = (const float*)d_in[5];
    const float* ln1_b   = (const float*)d_in[6];
    const float* Wq      = (const float*)d_in[7];
    const float* bq      = (const float*)d_in[8];
    const float* Wkv     = (const float*)d_in[9];
    const float* bkv     = (const float*)d_in[10];
    const float* We      = (const float*)d_in[11];
    const float* be      = (const float*)d_in[12];
    const float* Wo      = (const float*)d_in[13];
    const float* bo      = (const float*)d_in[14];
    const float* Wg1     = (const float*)d_in[15];
    const float* ln2_g   = (const float*)d_in[16];
    const float* ln2_b   = (const float*)d_in[17];
    const float* W1      = (const float*)d_in[18];
    const float* b1      = (const float*)d_in[19];
    const float* W2      = (const float*)d_in[20];
    const float* b2      = (const float*)d_in[21];
    const float* Wg2     = (const float*)d_in[22];
    const float* Wlin    = (const float*)d_in[23];
    const float* blin    = (const float*)d_in[24];

    float* ws    = (float*)d_ws;
    float* nodes = ws;                               // B*N*DIM   = 32768
    float* qb    = nodes + BB * NN * DIMM;           // B*N*INNER = 131072
    float* kb    = qb + BB * NN * INNER;
    float* vb    = kb + BB * NN * INNER;
    float* ao    = vb + BB * NN * INNER;

    k_pre<<<BB * NN, 512, 0, stream>>>(indices, noise, atom_emb, ln1_g, ln1_b,
                                       Wq, bq, Wkv, bkv, nodes, qb, kb, vb);
    for (int l = 0; l < DEPTH; l++) {
        k_attn<<<BB * NN, 1024, 0, stream>>>(l, coords, bonds, We, be, qb, kb, vb, ao);
        k_post<<<BB * NN, 512, 0, stream>>>(l, Wo, bo, Wg1, ln2_g, ln2_b, W1, b1, W2, b2,
                                            Wg2, ln1_g, ln1_b, Wq, bq, Wkv, bkv,
                                            nodes, qb, kb, vb, ao);
    }
    k_final<<<1, 256, 0, stream>>>(nodes, Wlin, blin, (float*)d_out);
}